// Round 2
// baseline (249.041 us; speedup 1.0000x reference)
//
#include <hip/hip_runtime.h>

// LIF neuron over [T, B, C, H, W] = [8, 32, 128, 32, 32] fp32.
// V_new = V + (-V/TAU + x_t); spike = (V_new>=1) - (V_new<=-1); hard reset.
//
// R1-R3: single-chain version pinned at 82 us / 2.4 TB/s (VGPR 24).
// R4-R6: 4-column MLP, nt ld/st. Harness 221.4 us.
// R7: preload-all-8-timesteps structure. Harness 241, rocprof ~96 us,
//     2.1 TB/s, VALUBusy 15%. FAILED STRUCTURALLY: VGPR_Count=28 proves
//     the compiler re-sank the loads into the compute loop (8 live
//     vfloat4 preloads alone need 32 VGPRs) -> only ~2-3 loads in
//     flight, latency-bound. One win confirmed: temporal loads halved
//     FETCH_SIZE to 64 MB (half of x stays L3-resident across replays).
// R8 (this): FORCE the preload with sched_barrier(0) after the load
//     phase. Scheduler cannot sink loads across it -> regalloc must
//     keep all 8 results live (VGPR >= ~44 expected; that counter is
//     the verification signal). In-order vmcnt retirement then makes
//     every consume wait at most vmcnt(7); stores (younger than all
//     loads) never gate a load-data wait. Temporal loads (L3 reuse),
//     nontemporal stores (don't evict x from L3) kept from R7.

#define T_STEPS 8

typedef float vfloat4 __attribute__((ext_vector_type(4)));

struct StepOut { float V; float o; };

__device__ __forceinline__ StepOut lif_step(float V, float x) {
    const float TAU = (float)(5.0 / 3.0);  // fp32, matches np cast
    // Replicate reference op order exactly: neg, IEEE divide, add, add.
    float dv = (-V) / TAU + x;
    float Vn = V + dv;
    float o = (Vn >= 1.0f ? 1.0f : 0.0f) - (Vn <= -1.0f ? 1.0f : 0.0f);
    StepOut r;
    r.o = o;
    r.V = (o == 0.0f) ? Vn : 0.0f;  // o is exactly -1/0/+1
    return r;
}

__device__ __forceinline__ vfloat4 lif_step4(vfloat4& V, vfloat4 xt) {
    StepOut a = lif_step(V.x, xt.x);
    StepOut b = lif_step(V.y, xt.y);
    StepOut c = lif_step(V.z, xt.z);
    StepOut d = lif_step(V.w, xt.w);
    vfloat4 Vn, o;
    Vn.x = a.V; Vn.y = b.V; Vn.z = c.V; Vn.w = d.V;
    o.x = a.o;  o.y = b.o;  o.z = c.o;  o.w = d.o;
    V = Vn;
    return o;
}

__global__ __launch_bounds__(256) void lif_kernel(const vfloat4* __restrict__ x,
                                                  vfloat4* __restrict__ out,
                                                  int n4) {
    const int i = blockIdx.x * blockDim.x + threadIdx.x;
    if (i >= n4) return;

    const size_t s = (size_t)n4;
    const size_t col = (size_t)i;

    // Phase 1: ALL 8 timestep loads issued back-to-back. Temporal: x is
    // 128 MiB, ~half stays resident in the 256 MiB L3 across replays
    // (measured: FETCH_SIZE = 64 MB with temporal vs 128 MB with nt).
    vfloat4 xs[T_STEPS];
#pragma unroll
    for (int t = 0; t < T_STEPS; ++t) {
        xs[t] = x[(size_t)t * s + col];
    }

    // Hard scheduling fence: nothing moves across this point. Forces
    // all 8 load results to be simultaneously live (VGPR >= 44) so the
    // memory pipeline really has 8 outstanding loads per thread.
    __builtin_amdgcn_sched_barrier(0);

    // Phase 2: serial V-chain (the only true dependency). Consuming
    // xs[t] in issue order needs at most vmcnt(7) each (7 younger vmem
    // ops); in-order retirement means stores never gate these waits.
    vfloat4 V = (vfloat4)(0.f);
#pragma unroll
    for (int t = 0; t < T_STEPS; ++t) {
        vfloat4 o = lif_step4(V, xs[t]);
        __builtin_nontemporal_store(o, &out[(size_t)t * s + col]);
    }
}

extern "C" void kernel_launch(void* const* d_in, const int* in_sizes, int n_in,
                              void* d_out, int out_size, void* d_ws, size_t ws_size,
                              hipStream_t stream) {
    const float* x = (const float*)d_in[0];
    float* out = (float*)d_out;

    int total = in_sizes[0];            // T*B*C*H*W = 33554432
    int n = total / T_STEPS;            // spatial elements per timestep
    int n4 = n / 4;                     // float4 groups = 1048576 threads

    dim3 block(256);
    dim3 grid((n4 + block.x - 1) / block.x);  // 4096 blocks
    lif_kernel<<<grid, block, 0, stream>>>((const vfloat4*)x, (vfloat4*)out, n4);
}

// Round 3
// 244.305 us; speedup vs baseline: 1.0194x; 1.0194x over previous
//
#include <hip/hip_runtime.h>

// LIF neuron over [T, B, C, H, W] = [8, 32, 128, 32, 32] fp32.
// V_new = V + (-V/TAU + x_t); spike = (V_new>=1) - (V_new<=-1); hard reset.
//
// R1-R3: single-chain, 82 us rocprof / 2.4 TB/s, VGPR 24.
// R4-R6: 4-column MLP, nt ld/st. Harness 221.4 us.
// R7: preload-all-T + temporal loads. rocprof ~96 us. VGPR=28 -> compiler
//     re-sank loads (structure never executed). Confirmed win: temporal
//     loads halve FETCH_SIZE to 64 MB (L3 keeps half of x across replays).
// R8: + sched_barrier(0). VGPR=24 -> STILL sunk (sched_barrier only fences
//     the scheduler, not sinking/remat). Duration invariant ~95 us.
//     KEY EVIDENCE: dispatch with x fully L3-resident (FETCH~3MB) ran the
//     SAME 96 us -> not read-BW-bound; latency/queue-bound with the
//     compiler's shallow 2-deep load pipeline (all variants 82-97 us).
// R9 (this): pin the 8 preloads with opaque inline asm ("+v" in/outs).
//     The values MUST be live in registers at the asm -> loads cannot
//     sink. Expect: 8 back-to-back global_load_dwordx4, one vmcnt(0),
//     then pure-register compute+store phase. VGPR >= 40 is the
//     verification signal. 8 KB/wave in flight, ~32 waves/CU -> read
//     side becomes bandwidth-fed. Temporal loads + nt stores kept.

#define T_STEPS 8

typedef float vfloat4 __attribute__((ext_vector_type(4)));

struct StepOut { float V; float o; };

__device__ __forceinline__ StepOut lif_step(float V, float x) {
    const float TAU = (float)(5.0 / 3.0);  // fp32, matches np cast
    // Replicate reference op order exactly: neg, IEEE divide, add, add.
    float dv = (-V) / TAU + x;
    float Vn = V + dv;
    float o = (Vn >= 1.0f ? 1.0f : 0.0f) - (Vn <= -1.0f ? 1.0f : 0.0f);
    StepOut r;
    r.o = o;
    r.V = (o == 0.0f) ? Vn : 0.0f;  // o is exactly -1/0/+1
    return r;
}

__device__ __forceinline__ vfloat4 lif_step4(vfloat4& V, vfloat4 xt) {
    StepOut a = lif_step(V.x, xt.x);
    StepOut b = lif_step(V.y, xt.y);
    StepOut c = lif_step(V.z, xt.z);
    StepOut d = lif_step(V.w, xt.w);
    vfloat4 Vn, o;
    Vn.x = a.V; Vn.y = b.V; Vn.z = c.V; Vn.w = d.V;
    o.x = a.o;  o.y = b.o;  o.z = c.o;  o.w = d.o;
    V = Vn;
    return o;
}

__global__ __launch_bounds__(256) void lif_kernel(const vfloat4* __restrict__ x,
                                                  vfloat4* __restrict__ out,
                                                  int n4) {
    const int i = blockIdx.x * blockDim.x + threadIdx.x;
    if (i >= n4) return;

    const size_t s = (size_t)n4;
    const size_t col = (size_t)i;

    // Phase 1: ALL 8 timestep loads, issued back-to-back. Temporal:
    // measured FETCH_SIZE = 64 MB (half of x stays L3-resident across
    // replays) vs 128 MB with nt loads.
    vfloat4 x0 = x[0 * s + col];
    vfloat4 x1 = x[1 * s + col];
    vfloat4 x2 = x[2 * s + col];
    vfloat4 x3 = x[3 * s + col];
    vfloat4 x4 = x[4 * s + col];
    vfloat4 x5 = x[5 * s + col];
    vfloat4 x6 = x[6 * s + col];
    vfloat4 x7 = x[7 * s + col];

    // Opaque register pin: all 8 load results must be physically live in
    // VGPRs here -> the loads CANNOT be sunk/rematerialized into the
    // compute loop (sched_barrier failed to guarantee this in R8; this
    // does). Forces 8 outstanding loads, then a single vmcnt(0).
    asm volatile("" : "+v"(x0), "+v"(x1), "+v"(x2), "+v"(x3),
                      "+v"(x4), "+v"(x5), "+v"(x6), "+v"(x7));

    // Phase 2: serial V-chain (the only true dependency), pure-register
    // inputs; stores stream out nontemporally (don't evict x from L3).
    vfloat4 V = (vfloat4)(0.f);
    vfloat4 o;
    o = lif_step4(V, x0); __builtin_nontemporal_store(o, &out[0 * s + col]);
    o = lif_step4(V, x1); __builtin_nontemporal_store(o, &out[1 * s + col]);
    o = lif_step4(V, x2); __builtin_nontemporal_store(o, &out[2 * s + col]);
    o = lif_step4(V, x3); __builtin_nontemporal_store(o, &out[3 * s + col]);
    o = lif_step4(V, x4); __builtin_nontemporal_store(o, &out[4 * s + col]);
    o = lif_step4(V, x5); __builtin_nontemporal_store(o, &out[5 * s + col]);
    o = lif_step4(V, x6); __builtin_nontemporal_store(o, &out[6 * s + col]);
    o = lif_step4(V, x7); __builtin_nontemporal_store(o, &out[7 * s + col]);
}

extern "C" void kernel_launch(void* const* d_in, const int* in_sizes, int n_in,
                              void* d_out, int out_size, void* d_ws, size_t ws_size,
                              hipStream_t stream) {
    const float* x = (const float*)d_in[0];
    float* out = (float*)d_out;

    int total = in_sizes[0];            // T*B*C*H*W = 33554432
    int n = total / T_STEPS;            // spatial elements per timestep
    int n4 = n / 4;                     // float4 groups = 1048576 threads

    dim3 block(256);
    dim3 grid((n4 + block.x - 1) / block.x);  // 4096 blocks
    lif_kernel<<<grid, block, 0, stream>>>((const vfloat4*)x, (vfloat4*)out, n4);
}

// Round 4
// 241.709 us; speedup vs baseline: 1.0303x; 1.0107x over previous
//
#include <hip/hip_runtime.h>

// LIF neuron over [T, B, C, H, W] = [8, 32, 128, 32, 32] fp32.
// V_new = V + (-V/TAU + x_t); spike = (V_new>=1) - (V_new<=-1); hard reset.
//
// R1-R3: single-chain, plain ld/st: 82 us rocprof / 2.4 TB/s, VGPR 24.
//        BEST rocprof number so far.
// R4-R6: 4-column MLP, nt ld/st. Harness 221.4 us.
// R7:    preload-all-T + temporal loads, nt stores. rocprof ~96 us,
//        VGPR=28 (loads re-sunk). Temporal loads: FETCH 128->64 MB.
// R8:    + sched_barrier(0). VGPR=24, no change. ~95 us.
// R9:    + inline-asm "+v" pin of all 8 preloads. VGPR=28 *identical to
//        R7* -> pin did not bind (or same binary). ~92.5 us. Conclusion:
//        per-thread MLP is not reachable through this compiler; duration
//        has been structure-invariant (82-97 us) across every load-side
//        variant. RETRACTED: R2's "x L3-resident at same dur" claim was
//        a NaN-FETCH misread (write-only hbm_bytes).
// R10 (this): SINGLE-VARIABLE TEST of the store path. The one thing all
//        ~92 us variants share (and the 82 us R1-R3 lacked) is
//        NONTEMPORAL stores: 128 MB / 92.5 us = 1.4 TB/s nt-write. If
//        the nt (no-allocate/write-through) TCC path caps store
//        throughput, it sets a structure-independent floor = exactly
//        what we observe. Flip stores to plain temporal
//        global_store_dwordx4 (write-allocate, full-line, lazy drain).
//        Loads stay temporal; preload+pin kept unchanged.
//        Predict: dur 92.5 -> 70-80 us if theory right (FETCH may rise
//        toward 128 MB as out evicts x -- improvement despite that
//        proves read side irrelevant); unchanged ~92 us kills the
//        theory -> pivot to occupancy/queue levers next.

#define T_STEPS 8

typedef float vfloat4 __attribute__((ext_vector_type(4)));

struct StepOut { float V; float o; };

__device__ __forceinline__ StepOut lif_step(float V, float x) {
    const float TAU = (float)(5.0 / 3.0);  // fp32, matches np cast
    // Replicate reference op order exactly: neg, IEEE divide, add, add.
    float dv = (-V) / TAU + x;
    float Vn = V + dv;
    float o = (Vn >= 1.0f ? 1.0f : 0.0f) - (Vn <= -1.0f ? 1.0f : 0.0f);
    StepOut r;
    r.o = o;
    r.V = (o == 0.0f) ? Vn : 0.0f;  // o is exactly -1/0/+1
    return r;
}

__device__ __forceinline__ vfloat4 lif_step4(vfloat4& V, vfloat4 xt) {
    StepOut a = lif_step(V.x, xt.x);
    StepOut b = lif_step(V.y, xt.y);
    StepOut c = lif_step(V.z, xt.z);
    StepOut d = lif_step(V.w, xt.w);
    vfloat4 Vn, o;
    Vn.x = a.V; Vn.y = b.V; Vn.z = c.V; Vn.w = d.V;
    o.x = a.o;  o.y = b.o;  o.z = c.o;  o.w = d.o;
    V = Vn;
    return o;
}

__global__ __launch_bounds__(256) void lif_kernel(const vfloat4* __restrict__ x,
                                                  vfloat4* __restrict__ out,
                                                  int n4) {
    const int i = blockIdx.x * blockDim.x + threadIdx.x;
    if (i >= n4) return;

    const size_t s = (size_t)n4;
    const size_t col = (size_t)i;

    // Phase 1: all 8 timestep loads, back-to-back, TEMPORAL (measured:
    // FETCH_SIZE 128->64 MB from L3 retention across replays).
    vfloat4 x0 = x[0 * s + col];
    vfloat4 x1 = x[1 * s + col];
    vfloat4 x2 = x[2 * s + col];
    vfloat4 x3 = x[3 * s + col];
    vfloat4 x4 = x[4 * s + col];
    vfloat4 x5 = x[5 * s + col];
    vfloat4 x6 = x[6 * s + col];
    vfloat4 x7 = x[7 * s + col];

    // Register pin (diagnostic: VGPR>=36 iff this binds; 24-28 means the
    // compiler sank the loads again and per-thread MLP is a dead end).
    asm volatile("" : "+v"(x0), "+v"(x1), "+v"(x2), "+v"(x3),
                      "+v"(x4), "+v"(x5), "+v"(x6), "+v"(x7));

    // Phase 2: serial V-chain; PLAIN TEMPORAL stores (the experiment).
    // Full 128B lines written per wave -> no RFO; write-allocate lets
    // dirty lines drain lazily instead of forcing the nt streaming path.
    vfloat4 V = (vfloat4)(0.f);
    vfloat4 o;
    o = lif_step4(V, x0); out[0 * s + col] = o;
    o = lif_step4(V, x1); out[1 * s + col] = o;
    o = lif_step4(V, x2); out[2 * s + col] = o;
    o = lif_step4(V, x3); out[3 * s + col] = o;
    o = lif_step4(V, x4); out[4 * s + col] = o;
    o = lif_step4(V, x5); out[5 * s + col] = o;
    o = lif_step4(V, x6); out[6 * s + col] = o;
    o = lif_step4(V, x7); out[7 * s + col] = o;
}

extern "C" void kernel_launch(void* const* d_in, const int* in_sizes, int n_in,
                              void* d_out, int out_size, void* d_ws, size_t ws_size,
                              hipStream_t stream) {
    const float* x = (const float*)d_in[0];
    float* out = (float*)d_out;

    int total = in_sizes[0];            // T*B*C*H*W = 33554432
    int n = total / T_STEPS;            // spatial elements per timestep
    int n4 = n / 4;                     // float4 groups = 1048576 threads

    dim3 block(256);
    dim3 grid((n4 + block.x - 1) / block.x);  // 4096 blocks
    lif_kernel<<<grid, block, 0, stream>>>((const vfloat4*)x, (vfloat4*)out, n4);
}

// Round 7
// 239.556 us; speedup vs baseline: 1.0396x; 1.0090x over previous
//
#include <hip/hip_runtime.h>

// LIF neuron over [T, B, C, H, W] = [8, 32, 128, 32, 32] fp32.
// V_new = V + (-V/TAU + x_t); spike = (V_new>=1) - (V_new<=-1); hard reset.
//
// R1-R3:  single-chain, plain ld/st: 82 us rocprof, VGPR 24.
// R4-R6:  4-col MLP, nt ld/st. Harness 221.4 us.
// R7-R9:  register-preload attempts (plain / sched_barrier / asm "+v"
//         pin): VGPR stuck at 24-28 -> compiler sinks the loads every
//         time; per-thread VGPR MLP is UNREACHABLE via this compiler.
//         All land 89-97 us @ ~2.2 TB/s, VALUBusy 15%, occ 65%.
//         Confirmed win kept: temporal loads halve FETCH to 64 MB.
// R10:    temporal stores vs nt: 89.8 vs 92.5 us (~3%). Keep temporal.
// R11-R13 (this — R11/R12 never ran, GPU acquisition timeouts): force
//         8-deep MLP through the LDS pipe instead of VGPRs.
//         __builtin_amdgcn_global_load_lds has NO VGPR destination ->
//         the compiler CANNOT sink/shrink it. Each wave fires 8 x 1KB
//         direct-to-LDS loads (8 KB/wave, ~160 KB/CU in flight),
//         __syncthreads() (compiler emits s_waitcnt vmcnt(0) before
//         s_barrier -- documented drain), then the serial V-chain reads
//         via ds_read_b128 (lgkmcnt pipe: store retirement can never
//         gate it). Load AND store latency fully decoupled from the
//         dependency chain, structurally.
//         Verification signals: LDS_Block_Size=32768, VGPR<=32.
//         Predict: 90 -> 50-65 us if latency-exposure theory is right;
//         ~90 us with LDS confirmed kills it -> systemic BW cap and the
//         strongest roofline evidence yet.

#define T_STEPS 8
#define BLOCK 256

typedef float vfloat4 __attribute__((ext_vector_type(4)));

typedef const __attribute__((address_space(1))) char* gsrc_ptr;
typedef __attribute__((address_space(3))) char* lds_dst_ptr;

struct StepOut { float V; float o; };

__device__ __forceinline__ StepOut lif_step(float V, float x) {
    const float TAU = (float)(5.0 / 3.0);  // fp32, matches np cast
    // Replicate reference op order exactly: neg, IEEE divide, add, add.
    float dv = (-V) / TAU + x;
    float Vn = V + dv;
    float o = (Vn >= 1.0f ? 1.0f : 0.0f) - (Vn <= -1.0f ? 1.0f : 0.0f);
    StepOut r;
    r.o = o;
    r.V = (o == 0.0f) ? Vn : 0.0f;  // o is exactly -1/0/+1
    return r;
}

__device__ __forceinline__ vfloat4 lif_step4(vfloat4& V, vfloat4 xt) {
    StepOut a = lif_step(V.x, xt.x);
    StepOut b = lif_step(V.y, xt.y);
    StepOut c = lif_step(V.z, xt.z);
    StepOut d = lif_step(V.w, xt.w);
    vfloat4 Vn, o;
    Vn.x = a.V; Vn.y = b.V; Vn.z = c.V; Vn.w = d.V;
    o.x = a.o;  o.y = b.o;  o.z = c.o;  o.w = d.o;
    V = Vn;
    return o;
}

__global__ __launch_bounds__(BLOCK) void lif_kernel(const vfloat4* __restrict__ x,
                                                    vfloat4* __restrict__ out,
                                                    int n4) {
    // [timestep][column-within-block]; thread tid's data lands at
    // lds[t][tid] because global_load_lds writes base + lane*16 and we
    // pass base = &lds[t][wave*64].
    __shared__ vfloat4 lds[T_STEPS][BLOCK];

    const int tid = threadIdx.x;
    const int col = blockIdx.x * BLOCK + tid;
    const size_t s = (size_t)n4;

    // Clamped source for (non-existent at this shape) tail blocks;
    // stores are guarded below, so clamped loads are harmless.
    const size_t colc = (size_t)(col < n4 ? col : n4 - 1);
    const int wbase = tid & ~63;  // wave-uniform LDS lane-0 slot

    // Phase 1: 8 fire-and-forget direct-to-LDS loads per wave.
    // No VGPR destination -> compiler cannot sink these into the
    // compute loop. 8 KB per wave guaranteed in flight. Temporal
    // (L3 keeps ~half of x across replays: FETCH 128->64 MB measured).
#pragma unroll
    for (int t = 0; t < T_STEPS; ++t) {
        __builtin_amdgcn_global_load_lds(
            (gsrc_ptr)(&x[(size_t)t * s + colc]),
            (lds_dst_ptr)(&lds[t][wbase]),
            16, 0, 0);
    }

    // Compiler emits s_waitcnt vmcnt(0) (drains the 8 LDS-loads) before
    // s_barrier. After this, everything the V-chain touches is in LDS.
    __syncthreads();

    // Phase 2: serial V-chain off ds_read_b128 (lgkmcnt pipe — the
    // store stream's vmcnt retirement can never gate these waits).
    // Stores are temporal (R10: ~3% better than nt) and simply queue.
    if (col < n4) {
        vfloat4 V = (vfloat4)(0.f);
#pragma unroll
        for (int t = 0; t < T_STEPS; ++t) {
            vfloat4 xt = lds[t][tid];
            vfloat4 o = lif_step4(V, xt);
            out[(size_t)t * s + col] = o;
        }
    }
}

extern "C" void kernel_launch(void* const* d_in, const int* in_sizes, int n_in,
                              void* d_out, int out_size, void* d_ws, size_t ws_size,
                              hipStream_t stream) {
    const float* x = (const float*)d_in[0];
    float* out = (float*)d_out;

    int total = in_sizes[0];            // T*B*C*H*W = 33554432
    int n = total / T_STEPS;            // spatial elements per timestep
    int n4 = n / 4;                     // float4 groups = 1048576

    dim3 block(BLOCK);
    dim3 grid((n4 + BLOCK - 1) / BLOCK);  // 4096 blocks, exact cover
    lif_kernel<<<grid, block, 0, stream>>>((const vfloat4*)x, (vfloat4*)out, n4);
}

// Round 8
// 231.060 us; speedup vs baseline: 1.0778x; 1.0368x over previous
//
#include <hip/hip_runtime.h>

// LIF neuron over [T, B, C, H, W] = [8, 32, 128, 32, 32] fp32.
// V_new = V + (-V/TAU + x_t); spike = (V_new>=1) - (V_new<=-1); hard reset.
//
// R1-R3:  single-chain, plain ld/st: 82 us rocprof, VGPR 24.
// R4-R6:  4-col MLP, nt ld/st. Harness 221.4 us — SESSION BEST on the
//         graded metric.
// R7-R9:  register-preload attempts (plain / sched_barrier / asm "+v"
//         pin): VGPR stuck 24-28 -> compiler always sinks the loads;
//         per-thread VGPR preload unreachable. All ~90-97 us rocprof.
//         Kept win: temporal loads halve FETCH to 64 MB (L3 retention).
// R10:    temporal stores vs nt: 89.8 vs 92.5 us. Keep temporal.
// R11:    DECISIVE: forced 8-deep MLP via global_load_lds (structure
//         PROVEN: LDS=32768, VGPR=44) -> 93-99 us, NO improvement; and
//         occupancy halved (65->34%) with NO duration change either.
//         Conclusion: ~2.15 TB/s combined (64 MB rd + 128 MB wr) is a
//         structure-invariant cap for this shape — invariant to load
//         depth (2 vs 8), occupancy (11 vs 21 waves/CU), store flavor
//         (±3%), staging path (VGPR vs LDS). ~4.7 B/cy/CU, under half
//         of copy-ubench's ~10 B/cy/CU.
// R14 (this): pivot to the graded harness metric. Revert to the
//         best-harness structure (R4: 4 independent V-chains/thread,
//         Q-strided, 4 chains x 2-deep compiler pipeline = 8
//         outstanding loads naturally) and flip ONLY the memory
//         flavors to the two measured wins: TEMPORAL loads (L3
//         retention) + TEMPORAL stores (R10 +3%). Predict harness
//         240 -> 205-218; if >=235, R4's 221.4 was noise -> declare
//         roofline on R11's structural evidence.

#define T_STEPS 8

typedef float vfloat4 __attribute__((ext_vector_type(4)));

struct StepOut { float V; float o; };

__device__ __forceinline__ StepOut lif_step(float V, float x) {
    const float TAU = (float)(5.0 / 3.0);  // fp32, matches np cast
    // Replicate reference op order exactly: neg, IEEE divide, add, add.
    float dv = (-V) / TAU + x;
    float Vn = V + dv;
    float o = (Vn >= 1.0f ? 1.0f : 0.0f) - (Vn <= -1.0f ? 1.0f : 0.0f);
    StepOut r;
    r.o = o;
    r.V = (o == 0.0f) ? Vn : 0.0f;  // o is exactly -1/0/+1
    return r;
}

__device__ __forceinline__ vfloat4 lif_step4(vfloat4& V, vfloat4 xt) {
    StepOut a = lif_step(V.x, xt.x);
    StepOut b = lif_step(V.y, xt.y);
    StepOut c = lif_step(V.z, xt.z);
    StepOut d = lif_step(V.w, xt.w);
    vfloat4 Vn, o;
    Vn.x = a.V; Vn.y = b.V; Vn.z = c.V; Vn.w = d.V;
    o.x = a.o;  o.y = b.o;  o.z = c.o;  o.w = d.o;
    V = Vn;
    return o;
}

__global__ __launch_bounds__(256) void lif_kernel(const vfloat4* __restrict__ x,
                                                  vfloat4* __restrict__ out,
                                                  int n4) {
    const int Q = n4 >> 2;  // columns per chain-slot (n4 divisible by 4)
    int q = blockIdx.x * blockDim.x + threadIdx.x;
    if (q >= Q) return;

    const size_t s = (size_t)n4;
    const size_t i0 = (size_t)q;
    const size_t i1 = (size_t)q + (size_t)Q;
    const size_t i2 = (size_t)q + 2 * (size_t)Q;
    const size_t i3 = (size_t)q + 3 * (size_t)Q;

    vfloat4 Va = (vfloat4)(0.f);
    vfloat4 Vb = Va, Vc = Va, Vd = Va;

#pragma unroll
    for (int t = 0; t < T_STEPS; ++t) {
        const size_t base = (size_t)t * s;
        // 4 independent TEMPORAL loads issued back-to-back; 4 chains x
        // compiler's 2-deep pipeline = 8 outstanding loads per wave.
        // Temporal: ~half of x stays L3-resident across harness replays
        // (measured FETCH 128 -> 64 MB vs nontemporal).
        vfloat4 xa = x[base + i0];
        vfloat4 xb = x[base + i1];
        vfloat4 xc = x[base + i2];
        vfloat4 xd = x[base + i3];

        vfloat4 oa = lif_step4(Va, xa);
        vfloat4 ob = lif_step4(Vb, xb);
        vfloat4 oc = lif_step4(Vc, xc);
        vfloat4 od = lif_step4(Vd, xd);

        // TEMPORAL stores (R10: ~3% faster than nontemporal).
        out[base + i0] = oa;
        out[base + i1] = ob;
        out[base + i2] = oc;
        out[base + i3] = od;
    }
}

extern "C" void kernel_launch(void* const* d_in, const int* in_sizes, int n_in,
                              void* d_out, int out_size, void* d_ws, size_t ws_size,
                              hipStream_t stream) {
    const float* x = (const float*)d_in[0];
    float* out = (float*)d_out;

    int total = in_sizes[0];            // T*B*C*H*W = 33554432
    int n = total / T_STEPS;            // spatial elements per timestep
    int n4 = n / 4;                     // float4 groups = 1048576
    int Q = n4 / 4;                     // threads = 262144

    dim3 block(256);
    dim3 grid((Q + block.x - 1) / block.x);  // 1024 blocks
    lif_kernel<<<grid, block, 0, stream>>>((const vfloat4*)x, (vfloat4*)out, n4);
}

// Round 10
// 228.140 us; speedup vs baseline: 1.0916x; 1.0128x over previous
//
#include <hip/hip_runtime.h>

// LIF neuron over [T, B, C, H, W] = [8, 32, 128, 32, 32] fp32.
// V_new = V + (-V/TAU + x_t); spike = (V_new>=1) - (V_new<=-1); hard reset.
//
// R1-R3:  single-chain, plain ld/st: 82 us rocprof, VGPR 24. 2.2 TB/s.
// R4-R6:  4-col MLP, nt ld/st. Harness 221.4 us (prev session).
// R7-R9:  register-preload attempts: compiler always sinks cross-barrier
//         preloads (VGPR pinned 24-28). ~90-97 us. Win kept: temporal
//         loads halve FETCH to 64 MB (L3 retention across replays).
// R10:    temporal stores beat nt by ~3%. Keep temporal.
// R11:    forced 8-deep MLP via global_load_lds + vmcnt(0) drain:
//         structure PROVEN (LDS=32768, VGPR=44), no improvement, occ
//         halved. Phase-drain structure is a dead end.
// R14:    4-col MLP + temporal ld/st: 80.6 us rocprof / 2.50 TB/s,
//         harness 231.1 — BEST. KEY COUNTER FINDS: (a) 4-col @34% occ
//         beats 1-col @65% occ -> per-wave MLP > occupancy here.
//         (b) harness's own fillBufferAligned: 6.7 TB/s (84% peak) at
//         9.9% occupancy, pure stores -> the "systemic ~2.2 TB/s cap"
//         theory from R11 is REFUTED; the machine has 2.5x headroom
//         over us, and low occupancy + deep MLP is a proven-good
//         operating point on this chip.
// R15/R16 (this — R15 never ran, GPU acquisition timeout): continue the
//         measured depth gradient: 8 independent chains/thread
//         (Q=n4/8, 512 blocks, 25% occ cap). Compiler issues same-BB
//         chain loads back-to-back (the R4 mechanism; it only refuses
//         cross-barrier preloads), so expect ~8 outstanding 1KB
//         loads/wave. Predict 80.6 -> 68-75 us, 2.8-3.0 TB/s if trend
//         holds; flat -> depth-saturated, revert to 4-col; worse ->
//         occupancy floor, revert to 4-col.

#define T_STEPS 8
#define NCOL 8

typedef float vfloat4 __attribute__((ext_vector_type(4)));

struct StepOut { float V; float o; };

__device__ __forceinline__ StepOut lif_step(float V, float x) {
    const float TAU = (float)(5.0 / 3.0);  // fp32, matches np cast
    // Replicate reference op order exactly: neg, IEEE divide, add, add.
    float dv = (-V) / TAU + x;
    float Vn = V + dv;
    float o = (Vn >= 1.0f ? 1.0f : 0.0f) - (Vn <= -1.0f ? 1.0f : 0.0f);
    StepOut r;
    r.o = o;
    r.V = (o == 0.0f) ? Vn : 0.0f;  // o is exactly -1/0/+1
    return r;
}

__device__ __forceinline__ vfloat4 lif_step4(vfloat4& V, vfloat4 xt) {
    StepOut a = lif_step(V.x, xt.x);
    StepOut b = lif_step(V.y, xt.y);
    StepOut c = lif_step(V.z, xt.z);
    StepOut d = lif_step(V.w, xt.w);
    vfloat4 Vn, o;
    Vn.x = a.V; Vn.y = b.V; Vn.z = c.V; Vn.w = d.V;
    o.x = a.o;  o.y = b.o;  o.z = c.o;  o.w = d.o;
    V = Vn;
    return o;
}

__global__ __launch_bounds__(256) void lif_kernel(const vfloat4* __restrict__ x,
                                                  vfloat4* __restrict__ out,
                                                  int n4) {
    const int Q = n4 >> 3;  // columns per chain-slot (n4 divisible by 8)
    int q = blockIdx.x * blockDim.x + threadIdx.x;
    if (q >= Q) return;

    const size_t s = (size_t)n4;

    // 8 independent V-chains per thread, Q-strided (wave-contiguous
    // 1 KB per stream per load). All indices compile-time after unroll
    // -> everything stays in registers (no scratch).
    vfloat4 V[NCOL];
#pragma unroll
    for (int c = 0; c < NCOL; ++c) V[c] = (vfloat4)(0.f);

#pragma unroll
    for (int t = 0; t < T_STEPS; ++t) {
        const size_t base = (size_t)t * s + (size_t)q;

        // 8 independent TEMPORAL loads, same basic block -> compiler
        // issues them back-to-back (R4-mechanism): ~8 KB/wave in flight.
        vfloat4 xv[NCOL];
#pragma unroll
        for (int c = 0; c < NCOL; ++c) {
            xv[c] = x[base + (size_t)c * (size_t)Q];
        }

        vfloat4 o[NCOL];
#pragma unroll
        for (int c = 0; c < NCOL; ++c) {
            o[c] = lif_step4(V[c], xv[c]);
        }

        // TEMPORAL stores (R10: ~3% better than nt).
#pragma unroll
        for (int c = 0; c < NCOL; ++c) {
            out[base + (size_t)c * (size_t)Q] = o[c];
        }
    }
}

extern "C" void kernel_launch(void* const* d_in, const int* in_sizes, int n_in,
                              void* d_out, int out_size, void* d_ws, size_t ws_size,
                              hipStream_t stream) {
    const float* x = (const float*)d_in[0];
    float* out = (float*)d_out;

    int total = in_sizes[0];            // T*B*C*H*W = 33554432
    int n = total / T_STEPS;            // spatial elements per timestep
    int n4 = n / 4;                     // float4 groups = 1048576
    int Q = n4 / 8;                     // threads = 131072

    dim3 block(256);
    dim3 grid((Q + block.x - 1) / block.x);  // 512 blocks
    lif_kernel<<<grid, block, 0, stream>>>((const vfloat4*)x, (vfloat4*)out, n4);
}